// Round 6
// baseline (251.207 us; speedup 1.0000x reference)
//
#include <hip/hip_runtime.h>
#include <hip/hip_fp16.h>

// RiRoIAlign on gfx950 — round 6.
// fp16 NHWC staging in ws, then gather with x-pair-fused 1KB contiguous loads:
// corners (y,x0),(y,x1) are adjacent pixels in NHWC -> one wave-load (64 lanes
// x 16B) covers one y-row pair of corners x all 256 channels (lanes 0-31: x0,
// 32-63: x1). 2 loads/sample (vs 4 scattered-segment loads), 8 in flight/bin.
// Clamp case safe: x_edge => w01=w11=0, garbage read x0-weight. 512 blocks x
// 1024 thr = exactly 2 blocks/CU (32 waves/CU), LDS 56KB.

typedef _Float16 h16;
typedef _Float16 h8 __attribute__((ext_vector_type(8)));   // 16 B

#define NS 196          // 14*14 sample points per roi
#define HW 65536        // 256*256
#define TWO_PI_F 6.283185307179586f
#define OPITCH 260      // gather LDS out-tile pitch (256 ch + pad)
#define TP 40           // transpose LDS pitch in halves

// ------- transpose+cvt: feat[b][ch][px] f32 -> ft[b][px][ch] f16 -------
__global__ __launch_bounds__(256) void transpose_kernel(
    const float* __restrict__ in, h16* __restrict__ out)
{
    __shared__ h16 lds[256 * TP];     // [px 0..255][ch 0..31], pitch TP
    const int t = threadIdx.x;
    const int a = t & 63;             // pixel/4 index within tile
    const int w = t >> 6;             // wave: channel octet

    const int b  = blockIdx.z;
    const int tc = blockIdx.y;        // channel tile (32 ch)
    const int tp = blockIdx.x;        // pixel tile (256 px)

    const float* ip = in + ((size_t)b * 256 + tc * 32 + w * 8) * HW + tp * 256 + a * 4;

    float4 v[8];
    #pragma unroll
    for (int j = 0; j < 8; ++j)
        v[j] = *(const float4*)(ip + (size_t)j * HW);   // ch w*8+j, px 4a..4a+3

    #pragma unroll
    for (int p = 0; p < 4; ++p) {
        h8 row;
        #pragma unroll
        for (int j = 0; j < 8; ++j)
            row[j] = (h16)(((const float*)&v[j])[p]);
        *(h8*)&lds[(a * 4 + p) * TP + w * 8] = row;
    }
    __syncthreads();

    h16* op = out + ((size_t)b * HW + (size_t)tp * 256) * 256 + tc * 32;
    #pragma unroll
    for (int k = 0; k < 4; ++k) {
        int px   = (t >> 2) + k * 64;
        int part = t & 3;
        h8 r = *(const h8*)&lds[px * TP + part * 8];
        *(h8*)(op + (size_t)px * 256 + part * 8) = r;
    }
}

// ---------------- gather from fp16 NHWC, x-pair fused ----------------
__global__ __launch_bounds__(1024, 8) void riroi_gather(
    const h16* __restrict__ ft, const float* __restrict__ rois,
    float* __restrict__ out)
{
    const int r    = blockIdx.x;
    const int tid  = threadIdx.x;
    const int lane = tid & 63;
    const int wave = tid >> 6;           // 0..15
    const int l32  = lane & 31;          // channel group (8 ch each)
    const int xs   = lane >> 5;          // 0: x0 column, 1: x1 column

    const float* roi = rois + r * 6;
    const int   b  = (int)roi[0];
    const float cw = roi[1] * 0.125f;
    const float ch = roi[2] * 0.125f;
    const float rw = fmaxf(roi[3] * 0.125f, 1.0f);
    const float rh = fmaxf(roi[4] * 0.125f, 1.0f);
    const float theta = roi[5];

    const float ind_f = theta * 8.0f / TWO_PI_F;
    const float fl    = floorf(ind_f);
    const float lvar  = ind_f - fl;
    const float rvar  = 1.0f - lvar;
    int ii = (int)fl;
    const int ind = ((ii % 8) + 8) & 7;

    const float cost = cosf(theta), sint = sinf(theta);
    const float bin_h = rh / 7.0f, bin_w = rw / 7.0f;

    __shared__ int   s_off[2][NS];       // element offset of (y0,x0) and (y1,x0)
    __shared__ float s_w[4][NS];         // w00,w01,w10,w11 (incl validity)
    __shared__ float s_out[49 * OPITCH]; // [bin][ch] plane-space

    if (tid < NS) {
        int iy = tid / 14, ix = tid - iy * 14;
        int py = iy >> 1, gy = iy & 1;
        int px = ix >> 1, gx = ix & 1;
        float yy = ((float)py + ((float)gy + 0.5f) * 0.5f) * bin_h - rh * 0.5f;
        float xx = ((float)px + ((float)gx + 0.5f) * 0.5f) * bin_w - rw * 0.5f;
        float x = xx * cost - yy * sint + cw;
        float y = xx * sint + yy * cost + ch;
        float vm = (y > -1.0f && y < 256.0f && x > -1.0f && x < 256.0f) ? 1.0f : 0.0f;
        float yc = fmaxf(y, 0.0f), xc = fmaxf(x, 0.0f);
        int y0 = (int)yc, x0 = (int)xc;
        int y1; float yv, xv;
        if (y0 >= 255) { y0 = 255; y1 = 255; yv = 255.0f; }
        else           { y1 = y0 + 1; yv = yc; }
        if (x0 >= 255) { x0 = 255;           xv = 255.0f; }
        else           {                     xv = xc; }
        float ly = yv - (float)y0, lx = xv - (float)x0;
        float hy = 1.0f - ly, hx = 1.0f - lx;
        s_w[0][tid] = hy * hx * vm;   // (y0,x0)
        s_w[1][tid] = hy * lx * vm;   // (y0,x1)  — 0 when x-edge
        s_w[2][tid] = ly * hx * vm;   // (y1,x0)
        s_w[3][tid] = ly * lx * vm;   // (y1,x1)  — 0 when x-edge
        s_off[0][tid] = (y0 * 256 + x0) << 8;   // h16-element offset of row pair
        s_off[1][tid] = (y1 * 256 + x0) << 8;
    }
    __syncthreads();

    // lane covers pixel x0+xs, channels 8*l32..8*l32+7
    const h16* fb = ft + (size_t)b * ((size_t)HW * 256) + (lane << 3);

    for (int bin = wave; bin < 49; bin += 16) {
        int py = bin / 7, px = bin - py * 7;
        int sbase = py * 28 + px * 2;
        float v[8] = {0.f, 0.f, 0.f, 0.f, 0.f, 0.f, 0.f, 0.f};
        #pragma unroll
        for (int k = 0; k < 4; ++k) {
            int s = sbase + (k & 1) + ((k & 2) ? 14 : 0);
            int   oA = s_off[0][s];
            int   oB = s_off[1][s];
            float wA = s_w[xs][s];        // y0 row: w00 (x0) / w01 (x1)
            float wB = s_w[2 + xs][s];    // y1 row: w10 (x0) / w11 (x1)
            h8 fA = *(const h8*)(fb + oA);   // 1KB contiguous across the wave
            h8 fB = *(const h8*)(fb + oB);
            #pragma unroll
            for (int i = 0; i < 8; ++i)
                v[i] += wA * (float)fA[i] + wB * (float)fB[i];
        }
        // fold x0/x1 halves: lanes 0..31 then hold all 4 corners for their 8 ch
        #pragma unroll
        for (int i = 0; i < 8; ++i)
            v[i] += __shfl_xor(v[i], 32);

        if (xs == 0) {
            // in-lane orientation blend: ch = 8*l32 + i -> plane j = i
            float res[8];
            #pragma unroll
            for (int i = 0; i < 8; ++i)
                res[i] = 0.25f * (rvar * v[i] + lvar * v[(i + 1) & 7]);
            float* dst = &s_out[bin * OPITCH + (l32 << 3)];
            *(float4*)dst       = make_float4(res[0], res[1], res[2], res[3]);
            *(float4*)(dst + 4) = make_float4(res[4], res[5], res[6], res[7]);
        }
    }
    __syncthreads();

    // coalesced writeback with orientation permutation (octet-local)
    const int ind_neg = (8 - ind) & 7;
    float* ob = out + (size_t)r * 12544;
    for (int i = tid << 2; i < 12544; i += 4096) {
        float4 vo;
        #pragma unroll
        for (int q = 0; q < 4; ++q) {
            int j   = i + q;
            int co  = j / 49;
            int bin = j - co * 49;
            int ci  = (co & ~7) | ((co + ind_neg) & 7);
            ((float*)&vo)[q] = s_out[bin * OPITCH + ci];
        }
        *(float4*)(ob + i) = vo;
    }
}

extern "C" void kernel_launch(void* const* d_in, const int* in_sizes, int n_in,
                              void* d_out, int out_size, void* d_ws, size_t ws_size,
                              hipStream_t stream) {
    const float* feat = (const float*)d_in[0];   // 2*256*256*256 f32
    const float* rois = (const float*)d_in[1];   // 512*6 f32
    float* out = (float*)d_out;                  // 512*256*7*7 f32

    h16* ft = (h16*)d_ws;                        // 2*65536*256 f16 = 67 MB
    transpose_kernel<<<dim3(256, 8, 2), dim3(256), 0, stream>>>(feat, ft);
    riroi_gather<<<dim3(512), dim3(1024), 0, stream>>>(ft, rois, out);
}